// Round 17
// baseline (50.590 us; speedup 1.0000x reference)
//
#include <hip/hip_runtime.h>
#include <float.h>
#include <math.h>

#define BB 8
#define HH 256
#define WW 256
#define NPIX 65536          // HH*WW
#define TOT (BB*NPIX)
#define KTOP 80
#define NTIL2 256           // 16x16 tiles of 16x16 per image (box9/nms)
#define TCAP 64             // max peaks per 16x16 tile (5x5 NMS spacing caps 36)
#define CAP 8192            // max candidates per batch
#define SELBINS 4096        // bits>>19
#define BNDCAP 1024
#define NBLK (BB*64)        // 512 (tsplat: 4-row strips)
#define NBLK2 (BB*NTIL2)    // 2048 (box9/nms)
#define PREF 12             // prefetch rounds in tsplat (covers nC <= 3072)
typedef unsigned long long ull;

// ============ fused 9x9 avg-pools -> prod, per-block min partials; zero hist+bcnt ============
// 16x16 output tile, 24x24 halo -> 8 blocks/CU for latency hiding
__global__ void __launch_bounds__(256)
k_box9(const float* __restrict__ vsm, float* __restrict__ prod,
       float* __restrict__ pmn,
       unsigned* __restrict__ histg, unsigned* __restrict__ bcnt) {
    int blk = blockIdx.x;            // b*256 + t
    int b = blk >> 8, t = blk & 255;
    int ty0 = (t >> 4) << 4, tx0 = (t & 15) << 4;
    int tid = threadIdx.x;

    if (tid < 16) histg[b * SELBINS + t * 16 + tid] = 0u;   // 256 tiles x 16 bins
    if (blk < BB && tid == 0) bcnt[blk] = 0u;

    __shared__ float val[24][24];
    __shared__ float rs_o[24][16];
    __shared__ float rs_m[24][16];
    for (int i = tid; i < 576; i += 256) {
        int ly = i / 24, lx = i - ly * 24;
        int gy = ty0 - 4 + ly, gx = tx0 - 4 + lx;
        float v = 0.f;
        if (gy >= 0 && gy < HH && gx >= 0 && gx < WW) v = vsm[(b * HH + gy) * WW + gx];
        val[ly][lx] = v;
    }
    __syncthreads();
    for (int i = tid; i < 384; i += 256) {
        int ly = i >> 4, lx = i & 15;
        float so = 0.f, sm = 0.f;
        #pragma unroll
        for (int d = 0; d < 9; ++d) { float v = val[ly][lx + d]; so += (v > 0.2f) ? 1.f : 0.f; sm += v; }
        rs_o[ly][lx] = so; rs_m[ly][lx] = sm;
    }
    __syncthreads();
    int ox = tid & 15, oy = tid >> 4;        // one output per thread
    float so = 0.f, sm = 0.f;
    #pragma unroll
    for (int d = 0; d < 9; ++d) { so += rs_o[oy + d][ox]; sm += rs_m[oy + d][ox]; }
    float p = (so * (1.f / 81.f)) * (sm * (1.f / 81.f));
    prod[(b * HH + ty0 + oy) * WW + tx0 + ox] = p;

    float tmn = p;
    #pragma unroll
    for (int o = 32; o > 0; o >>= 1) tmn = fminf(tmn, __shfl_xor(tmn, o, 64));
    __shared__ float wmn[4];
    if ((tid & 63) == 0) wmn[tid >> 6] = tmn;
    __syncthreads();
    if (tid == 0) pmn[blk] = fminf(fminf(wmn[0], wmn[1]), fminf(wmn[2], wmn[3]));
}

// ============ score = vsm*(prod-mn) + 5x5 NMS + per-batch compact (packed keys) + histogram ============
// 16x16 output tile, 20x20 halo
__global__ void __launch_bounds__(256)
k_nms(const float* __restrict__ vsm, const float* __restrict__ prod,
      const float* __restrict__ pmn,
      unsigned* __restrict__ bcnt, ull* __restrict__ candK,
      unsigned* __restrict__ histg) {
    int blk = blockIdx.x;
    int b = blk >> 8, t = blk & 255;
    int ty0 = (t >> 4) << 4, tx0 = (t & 15) << 4;
    int tid = threadIdx.x;
    int lane = tid & 63, wid = tid >> 6;

    // ---- hoist halo loads (independent of mnp) so they overlap the pmn reduce ----
    float hv[2], hp[2];
    #pragma unroll
    for (int u = 0; u < 2; ++u) {
        int i = tid + u * 256;
        int ly = i / 20, lx = i - ly * 20;
        int gy = ty0 - 2 + ly, gx = tx0 - 2 + lx;
        bool ok = (i < 400) && gy >= 0 && gy < HH && gx >= 0 && gx < WW;
        int idx = ok ? (b * HH + gy) * WW + gx : 0;
        hv[u] = vsm[idx];
        hp[u] = prod[idx];
    }

    // ---- per-batch prod-min from 256 partials ----
    __shared__ float wmn[4];
    float mn = pmn[b * NTIL2 + tid];
    #pragma unroll
    for (int o = 32; o > 0; o >>= 1) mn = fminf(mn, __shfl_xor(mn, o, 64));
    if (lane == 0) wmn[wid] = mn;
    __syncthreads();
    float mnp = fminf(fminf(wmn[0], wmn[1]), fminf(wmn[2], wmn[3]));

    __shared__ float sc[20][20];
    __shared__ float hm[20][16];
    #pragma unroll
    for (int u = 0; u < 2; ++u) {
        int i = tid + u * 256;
        if (i < 400) {
            int ly = i / 20, lx = i - ly * 20;
            int gy = ty0 - 2 + ly, gx = tx0 - 2 + lx;
            bool ok = gy >= 0 && gy < HH && gx >= 0 && gx < WW;
            sc[ly][lx] = ok ? hv[u] * (hp[u] - mnp) : -FLT_MAX;
        }
    }
    __syncthreads();
    for (int i = tid; i < 320; i += 256) {
        int ly = i >> 4, lx = i & 15;
        float m = sc[ly][lx];
        #pragma unroll
        for (int d = 1; d < 5; ++d) m = fmaxf(m, sc[ly][lx + d]);
        hm[ly][lx] = m;
    }
    __syncthreads();
    __shared__ unsigned scnt;
    __shared__ unsigned sbase;
    __shared__ float bv[TCAP];
    __shared__ int bi[TCAP];
    if (tid == 0) scnt = 0;
    __syncthreads();
    int ox = tid & 15, oy = tid >> 4;
    float m = hm[oy][ox];
    #pragma unroll
    for (int d = 1; d < 5; ++d) m = fmaxf(m, hm[oy + d][ox]);
    float s = sc[oy + 2][ox + 2];
    if (s == m && s > 0.f) {
        unsigned p = atomicAdd(&scnt, 1u);
        if (p < TCAP) { bv[p] = s; bi[p] = (ty0 + oy) * WW + tx0 + ox; }
    }
    __syncthreads();
    unsigned cnt = min(scnt, (unsigned)TCAP);
    if (tid == 0) sbase = cnt ? atomicAdd(&bcnt[b], cnt) : 0u;   // ONE global atomic per tile
    __syncthreads();
    unsigned base = sbase;
    for (unsigned i = tid; i < cnt; i += 256) {
        unsigned pos = base + i;
        if (pos < CAP) {
            unsigned bits = __float_as_uint(bv[i]);
            candK[b * CAP + pos] = ((ull)bits << 32) | (ull)(0xFFFFFFFFu - (unsigned)bi[i]);
            atomicAdd(&histg[b * SELBINS + (bits >> 19)], 1u);
        }
    }
}

// ============ fused: thin per-block top-80 set + log-domain splat + normalization ============
__global__ void __launch_bounds__(256)
k_tsplat(const float* __restrict__ depth, const unsigned* __restrict__ bcnt,
         const ull* __restrict__ candK, const unsigned* __restrict__ histg,
         float* __restrict__ out) {
    int blk = blockIdx.x;
    int b = blk >> 6;
    int y0 = (blk & 63) << 2;
    int tid = threadIdx.x;
    int lane = tid & 63;
    int wid = tid >> 6;

    __shared__ ull acc[KTOP];
    __shared__ ull bnd[BNDCAP];
    __shared__ float4 lpf[KTOP];
    __shared__ unsigned wtot[4];
    __shared__ int sB;
    __shared__ unsigned nAccS, nBndS, svm, fcnt;

    if (tid == 0) { sB = 0; nAccS = 0; nBndS = 0; svm = 0; fcnt = 0; }
    if (tid < KTOP) acc[tid] = 0ull;

    // ---- prefetch candidate keys (independent of B) so they overlap the hist scan ----
    int nC = min((int)bcnt[b], CAP);
    ull kreg[PREF];
    #pragma unroll
    for (int u = 0; u < PREF; ++u) {
        int i = tid + u * 256;
        kreg[u] = (i < nC) ? candK[b * CAP + i] : 0ull;   // real keys are nonzero (val>0)
    }
    __syncthreads();                                       // barrier 1

    // ---- hierarchical suffix scan of prebuilt histogram (shfl-based) ----
    {
        const unsigned* hg = histg + b * SELBINS;
        int j0 = tid * 16;
        unsigned h[16]; unsigned part = 0;
        #pragma unroll
        for (int j = 0; j < 16; j += 4) {
            uint4 q = *reinterpret_cast<const uint4*>(hg + j0 + j);
            h[j] = q.x; h[j+1] = q.y; h[j+2] = q.z; h[j+3] = q.w;
            part += q.x + q.y + q.z + q.w;
        }
        unsigned suf = part;                               // inclusive suffix within wave
        #pragma unroll
        for (int off = 1; off < 64; off <<= 1) {
            unsigned v = __shfl_down(suf, off, 64);
            if (lane + off < 64) suf += v;
        }
        if (lane == 0) wtot[wid] = suf;                    // wave total
        __syncthreads();                                   // barrier 2
        unsigned above_waves = 0;
        #pragma unroll
        for (int w = 0; w < 4; ++w) if (w > wid) above_waves += wtot[w];
        unsigned run = above_waves + (suf - part);         // suffix over threads > tid
        for (int j = 15; j >= 0; --j) {
            unsigned hj = h[j];
            run += hj;                                     // run == suffix(j0+j)
            if (run >= KTOP && run - hj < KTOP) sB = j0 + j;
        }
        __syncthreads();                                   // barrier 3
    }
    int B = sB;

    // ---- filter prefetched keys: bins>B unsorted accept, bin==B staged ----
    #pragma unroll
    for (int u = 0; u < PREF; ++u) {
        ull key = kreg[u];
        if (key) {
            unsigned bits = (unsigned)(key >> 32);
            int bin = (int)(bits >> 19);
            if (bin >= B) {
                atomicMax(&svm, bits);                     // vmax (positive: bit order == value order)
                if (bin > B) {
                    unsigned p = atomicAdd(&nAccS, 1u);
                    if (p < KTOP) acc[p] = key;            // suffix(B+1) < 80 by scan construction
                } else {
                    unsigned q2 = atomicAdd(&nBndS, 1u);
                    if (q2 < BNDCAP) bnd[q2] = key;
                }
            }
        }
    }
    // tail (only if nC > PREF*256)
    for (int i = tid + PREF * 256; i < nC; i += 256) {
        ull key = candK[b * CAP + i];
        unsigned bits = (unsigned)(key >> 32);
        int bin = (int)(bits >> 19);
        if (bin >= B) {
            atomicMax(&svm, bits);
            if (bin > B) {
                unsigned p = atomicAdd(&nAccS, 1u);
                if (p < KTOP) acc[p] = key;
            } else {
                unsigned q2 = atomicAdd(&nBndS, 1u);
                if (q2 < BNDCAP) bnd[q2] = key;
            }
        }
    }
    __syncthreads();                                       // barrier 4
    unsigned nAcc = min(nAccS, (unsigned)KTOP);
    unsigned nBnd = min(nBndS, (unsigned)BNDCAP);
    unsigned quota = (KTOP > nAcc) ? (KTOP - nAcc) : 0u;
    if (quota > nBnd) quota = nBnd;

    // ---- parallel rank-select in boundary bin (LDS broadcast; keys distinct -> exact set) ----
    for (int i = tid; i < (int)nBnd; i += 256) {
        ull mykey = bnd[i];
        unsigned rank = 0;
        for (unsigned j = 0; j < nBnd; ++j) rank += (bnd[j] > mykey) ? 1u : 0u;
        if (rank < quota) acc[nAcc + rank] = mykey;
    }
    __syncthreads();                                       // barrier 5

    // ---- peak params + y-band prune into lpf ----
    float vmax = __uint_as_float(svm);
    float thr = log2f(vmax + 1e-30f) - 11.f;               // drop contributions < 2^-11 * vmax
    unsigned nTot = nAcc + quota;
    if (tid < (int)nTot) {
        ull key = acc[tid];
        if (key) {
            unsigned bits = (unsigned)(key >> 32);
            int idx = (int)(0xFFFFFFFFu - (unsigned)(key & 0xFFFFFFFFu));
            float val = __uint_as_float(bits);
            float plog = log2f(val);
            float fy = (float)(idx >> 8);
            float z = fmaxf(depth[b * NPIX + idx], 0.001f);
            float r = fminf(fmaxf(14.f / z, 1.5f), 18.f);
            float s2 = 0.36f * r * r;                      // (0.6*r)^2
            float c = 1.44269504f / (2.f * s2 + 1e-6f);    // log2(e)/denom
            float dymin = 0.f;
            if (fy < (float)y0) dymin = (float)y0 - fy;
            else if (fy > (float)(y0 + 3)) dymin = fy - (float)(y0 + 3);
            if (plog - dymin * dymin * c >= thr) {
                unsigned p = atomicAdd(&fcnt, 1u);
                lpf[p] = make_float4(plog, (float)(idx & 255), fy, c);
            }
        }
    }
    __syncthreads();                                       // barrier 6
    int m = (int)fcnt;

    // ---- log-domain splat, 4 rows/block, fused 1/vmax normalization ----
    float fx = (float)tid, fyv = (float)y0;
    float g0 = -INFINITY, g1 = -INFINITY, g2 = -INFINITY, g3 = -INFINITY;
    #pragma unroll 4
    for (int k = 0; k < m; ++k) {
        float4 q = lpf[k];                   // {plog, px, py, c}
        float dx = fx - q.y;
        float dx2 = dx * dx;
        float dy = fyv - q.z;
        float d2;
        d2 = fmaf(dy, dy, dx2);              g0 = fmaxf(g0, fmaf(-d2, q.w, q.x));
        float dyb = dy + 1.f;
        d2 = fmaf(dyb, dyb, dx2);            g1 = fmaxf(g1, fmaf(-d2, q.w, q.x));
        float dyc = dy + 2.f;
        d2 = fmaf(dyc, dyc, dx2);            g2 = fmaxf(g2, fmaf(-d2, q.w, q.x));
        float dyd = dy + 3.f;
        d2 = fmaf(dyd, dyd, dx2);            g3 = fmaxf(g3, fmaf(-d2, q.w, q.x));
    }
    float inv = 1.f / (vmax + 1e-6f);
    int base = (b * HH + y0) * WW + tid;
    out[base]          = exp2f(g0) * inv;
    out[base + WW]     = exp2f(g1) * inv;
    out[base + 2 * WW] = exp2f(g2) * inv;
    out[base + 3 * WW] = exp2f(g3) * inv;
}

extern "C" void kernel_launch(void* const* d_in, const int* in_sizes, int n_in,
                              void* d_out, int out_size, void* d_ws, size_t ws_size,
                              hipStream_t stream) {
    const float* vsm   = (const float*)d_in[0];
    const float* depth = (const float*)d_in[1];
    float* out = (float*)d_out;

    // workspace layout
    float* prod  = (float*)d_ws;                       // TOT
    float* pmn   = prod + TOT;                         // NBLK2 (2048)
    unsigned* bcnt  = (unsigned*)(pmn + NBLK2);        // BB
    unsigned* histg = bcnt + BB;                       // BB*SELBINS (16B-aligned offset)
    ull* candK = (ull*)(histg + BB * SELBINS);         // BB*CAP (8B-aligned)

    k_box9  <<<NBLK2, 256, 0, stream>>>(vsm, prod, pmn, histg, bcnt);
    k_nms   <<<NBLK2, 256, 0, stream>>>(vsm, prod, pmn, bcnt, candK, histg);
    k_tsplat<<<NBLK, 256, 0, stream>>>(depth, bcnt, candK, histg, out);
}

// Round 18
// 45.713 us; speedup vs baseline: 1.1067x; 1.1067x over previous
//
#include <hip/hip_runtime.h>
#include <float.h>
#include <math.h>

#define BB 8
#define HH 256
#define WW 256
#define NPIX 65536          // HH*WW
#define TOT (BB*NPIX)
#define KTOP 80
#define NTIL 64             // 8x8 tiles of 32x32 per image
#define TCAP 128            // max peaks per 32x32 tile (5x5 NMS spacing caps ~121)
#define CAP 8192            // max candidates per batch
#define SELBINS 4096        // bits>>19
#define BNDCAP 1024
#define NBLK (BB*NTIL)      // 512
#define PREF 12             // prefetch rounds in tsplat (covers nC <= 3072)
typedef unsigned long long ull;

// ============ fused 9x9 avg-pools -> prod, global atomicMin for per-batch min; zero hist+bcnt ============
__global__ void k_box9(const float* __restrict__ vsm, float* __restrict__ prod,
                       unsigned* __restrict__ pmnG,
                       unsigned* __restrict__ histg, unsigned* __restrict__ bcnt) {
    int blk = blockIdx.x;
    int b = blk >> 6, t = blk & 63;
    int ty0 = (t >> 3) << 5, tx0 = (t & 7) << 5;
    int tid = threadIdx.x;

    if (tid < 64) histg[b * SELBINS + t * 64 + tid] = 0u;
    if (blk < BB && tid == 0) bcnt[blk] = 0u;

    __shared__ float val[40][40];
    __shared__ float rs_o[40][32];
    __shared__ float rs_m[40][32];
    for (int i = tid; i < 1600; i += 256) {
        int ly = i / 40, lx = i - ly * 40;
        int gy = ty0 - 4 + ly, gx = tx0 - 4 + lx;
        float v = 0.f;
        if (gy >= 0 && gy < HH && gx >= 0 && gx < WW) v = vsm[(b * HH + gy) * WW + gx];
        val[ly][lx] = v;
    }
    __syncthreads();
    for (int i = tid; i < 1280; i += 256) {
        int ly = i >> 5, lx = i & 31;
        float so = 0.f, sm = 0.f;
        #pragma unroll
        for (int d = 0; d < 9; ++d) { float v = val[ly][lx + d]; so += (v > 0.2f) ? 1.f : 0.f; sm += v; }
        rs_o[ly][lx] = so; rs_m[ly][lx] = sm;
    }
    __syncthreads();
    int ox = tid & 31, oy0 = (tid >> 5) << 2;
    float tmn = FLT_MAX;
    #pragma unroll
    for (int j = 0; j < 4; ++j) {
        int oy = oy0 + j;
        float so = 0.f, sm = 0.f;
        #pragma unroll
        for (int d = 0; d < 9; ++d) { so += rs_o[oy + d][ox]; sm += rs_m[oy + d][ox]; }
        float p = (so * (1.f / 81.f)) * (sm * (1.f / 81.f));
        prod[(b * HH + ty0 + oy) * WW + tx0 + ox] = p;
        tmn = fminf(tmn, p);
    }
    #pragma unroll
    for (int o = 32; o > 0; o >>= 1) tmn = fminf(tmn, __shfl_xor(tmn, o, 64));
    __shared__ float wmn[4];
    if ((tid & 63) == 0) wmn[tid >> 6] = tmn;
    __syncthreads();
    if (tid == 0) {
        float m = fminf(fminf(wmn[0], wmn[1]), fminf(wmn[2], wmn[3]));
        // prod >= 0: positive-float bit order == value order; pmnG memset to 0xFFFFFFFF
        atomicMin(&pmnG[b], __float_as_uint(m));          // ONE global atomic per block (64/address)
    }
}

// ============ score = vsm*(prod-mn) + 5x5 NMS + per-batch compact (packed keys) + histogram ============
__global__ void k_nms(const float* __restrict__ vsm, const float* __restrict__ prod,
                      const unsigned* __restrict__ pmnG,
                      unsigned* __restrict__ bcnt, ull* __restrict__ candK,
                      unsigned* __restrict__ histg) {
    int blk = blockIdx.x;
    int b = blk >> 6, t = blk & 63;
    int ty0 = (t >> 3) << 5, tx0 = (t & 7) << 5;
    int tid = threadIdx.x;

    // ---- hoist halo loads (independent of mnp) so they overlap the pmn broadcast load ----
    float hv[6], hp[6];
    #pragma unroll
    for (int u = 0; u < 6; ++u) {
        int i = tid + u * 256;
        int ly = i / 36, lx = i - ly * 36;
        int gy = ty0 - 2 + ly, gx = tx0 - 2 + lx;
        bool ok = (i < 1296) && gy >= 0 && gy < HH && gx >= 0 && gx < WW;
        int idx = ok ? (b * HH + gy) * WW + gx : 0;
        hv[u] = vsm[idx];
        hp[u] = prod[idx];
    }

    // single broadcast scalar (kernel boundary guarantees all box9 atomics done)
    float mnp = __uint_as_float(pmnG[b]);

    __shared__ float sc[36][36];
    __shared__ float hm[36][32];
    #pragma unroll
    for (int u = 0; u < 6; ++u) {
        int i = tid + u * 256;
        if (i < 1296) {
            int ly = i / 36, lx = i - ly * 36;
            int gy = ty0 - 2 + ly, gx = tx0 - 2 + lx;
            bool ok = gy >= 0 && gy < HH && gx >= 0 && gx < WW;
            sc[ly][lx] = ok ? hv[u] * (hp[u] - mnp) : -FLT_MAX;
        }
    }
    __syncthreads();
    for (int i = tid; i < 1152; i += 256) {
        int ly = i >> 5, lx = i & 31;
        float m = sc[ly][lx];
        #pragma unroll
        for (int d = 1; d < 5; ++d) m = fmaxf(m, sc[ly][lx + d]);
        hm[ly][lx] = m;
    }
    __syncthreads();
    __shared__ unsigned scnt;
    __shared__ unsigned sbase;
    __shared__ float bv[TCAP];
    __shared__ int bi[TCAP];
    if (tid == 0) scnt = 0;
    __syncthreads();
    int ox = tid & 31, oy0 = (tid >> 5) << 2;
    #pragma unroll
    for (int j = 0; j < 4; ++j) {
        int oy = oy0 + j;
        float m = hm[oy][ox];
        #pragma unroll
        for (int d = 1; d < 5; ++d) m = fmaxf(m, hm[oy + d][ox]);
        float s = sc[oy + 2][ox + 2];
        if (s == m && s > 0.f) {
            unsigned p = atomicAdd(&scnt, 1u);
            if (p < TCAP) { bv[p] = s; bi[p] = (ty0 + oy) * WW + tx0 + ox; }
        }
    }
    __syncthreads();
    unsigned cnt = min(scnt, (unsigned)TCAP);
    if (tid == 0) sbase = cnt ? atomicAdd(&bcnt[b], cnt) : 0u;   // ONE global atomic per tile
    __syncthreads();
    unsigned base = sbase;
    for (unsigned i = tid; i < cnt; i += 256) {
        unsigned pos = base + i;
        if (pos < CAP) {
            unsigned bits = __float_as_uint(bv[i]);
            candK[b * CAP + pos] = ((ull)bits << 32) | (ull)(0xFFFFFFFFu - (unsigned)bi[i]);
            atomicAdd(&histg[b * SELBINS + (bits >> 19)], 1u);
        }
    }
}

// ============ fused: thin per-block top-80 set + log-domain splat + normalization ============
__global__ void __launch_bounds__(256)
k_tsplat(const float* __restrict__ depth, const unsigned* __restrict__ bcnt,
         const ull* __restrict__ candK, const unsigned* __restrict__ histg,
         float* __restrict__ out) {
    int blk = blockIdx.x;
    int b = blk >> 6;
    int y0 = (blk & 63) << 2;
    int tid = threadIdx.x;
    int lane = tid & 63;
    int wid = tid >> 6;

    __shared__ ull acc[KTOP];
    __shared__ ull bnd[BNDCAP];
    __shared__ float4 lpf[KTOP];
    __shared__ unsigned wtot[4];
    __shared__ int sB;
    __shared__ unsigned nAccS, nBndS, svm, fcnt;

    if (tid == 0) { sB = 0; nAccS = 0; nBndS = 0; svm = 0; fcnt = 0; }
    if (tid < KTOP) acc[tid] = 0ull;

    // ---- prefetch candidate keys (independent of B) so they overlap the hist scan ----
    int nC = min((int)bcnt[b], CAP);
    ull kreg[PREF];
    #pragma unroll
    for (int u = 0; u < PREF; ++u) {
        int i = tid + u * 256;
        kreg[u] = (i < nC) ? candK[b * CAP + i] : 0ull;   // real keys are nonzero (val>0)
    }
    __syncthreads();                                       // barrier 1

    // ---- hierarchical suffix scan of prebuilt histogram (shfl-based) ----
    {
        const unsigned* hg = histg + b * SELBINS;
        int j0 = tid * 16;
        unsigned h[16]; unsigned part = 0;
        #pragma unroll
        for (int j = 0; j < 16; j += 4) {
            uint4 q = *reinterpret_cast<const uint4*>(hg + j0 + j);
            h[j] = q.x; h[j+1] = q.y; h[j+2] = q.z; h[j+3] = q.w;
            part += q.x + q.y + q.z + q.w;
        }
        unsigned suf = part;                               // inclusive suffix within wave
        #pragma unroll
        for (int off = 1; off < 64; off <<= 1) {
            unsigned v = __shfl_down(suf, off, 64);
            if (lane + off < 64) suf += v;
        }
        if (lane == 0) wtot[wid] = suf;                    // wave total
        __syncthreads();                                   // barrier 2
        unsigned above_waves = 0;
        #pragma unroll
        for (int w = 0; w < 4; ++w) if (w > wid) above_waves += wtot[w];
        unsigned run = above_waves + (suf - part);         // suffix over threads > tid
        for (int j = 15; j >= 0; --j) {
            unsigned hj = h[j];
            run += hj;                                     // run == suffix(j0+j)
            if (run >= KTOP && run - hj < KTOP) sB = j0 + j;
        }
        __syncthreads();                                   // barrier 3
    }
    int B = sB;

    // ---- filter prefetched keys: bins>B unsorted accept, bin==B staged ----
    #pragma unroll
    for (int u = 0; u < PREF; ++u) {
        ull key = kreg[u];
        if (key) {
            unsigned bits = (unsigned)(key >> 32);
            int bin = (int)(bits >> 19);
            if (bin >= B) {
                atomicMax(&svm, bits);                     // vmax (positive: bit order == value order)
                if (bin > B) {
                    unsigned p = atomicAdd(&nAccS, 1u);
                    if (p < KTOP) acc[p] = key;            // suffix(B+1) < 80 by scan construction
                } else {
                    unsigned q2 = atomicAdd(&nBndS, 1u);
                    if (q2 < BNDCAP) bnd[q2] = key;
                }
            }
        }
    }
    // tail (only if nC > PREF*256)
    for (int i = tid + PREF * 256; i < nC; i += 256) {
        ull key = candK[b * CAP + i];
        unsigned bits = (unsigned)(key >> 32);
        int bin = (int)(bits >> 19);
        if (bin >= B) {
            atomicMax(&svm, bits);
            if (bin > B) {
                unsigned p = atomicAdd(&nAccS, 1u);
                if (p < KTOP) acc[p] = key;
            } else {
                unsigned q2 = atomicAdd(&nBndS, 1u);
                if (q2 < BNDCAP) bnd[q2] = key;
            }
        }
    }
    __syncthreads();                                       // barrier 4
    unsigned nAcc = min(nAccS, (unsigned)KTOP);
    unsigned nBnd = min(nBndS, (unsigned)BNDCAP);
    unsigned quota = (KTOP > nAcc) ? (KTOP - nAcc) : 0u;
    if (quota > nBnd) quota = nBnd;

    // ---- parallel rank-select in boundary bin (LDS broadcast; keys distinct -> exact set) ----
    for (int i = tid; i < (int)nBnd; i += 256) {
        ull mykey = bnd[i];
        unsigned rank = 0;
        for (unsigned j = 0; j < nBnd; ++j) rank += (bnd[j] > mykey) ? 1u : 0u;
        if (rank < quota) acc[nAcc + rank] = mykey;
    }
    __syncthreads();                                       // barrier 5

    // ---- peak params + y-band prune into lpf ----
    float vmax = __uint_as_float(svm);
    float thr = log2f(vmax + 1e-30f) - 11.f;               // drop contributions < 2^-11 * vmax
    unsigned nTot = nAcc + quota;
    if (tid < (int)nTot) {
        ull key = acc[tid];
        if (key) {
            unsigned bits = (unsigned)(key >> 32);
            int idx = (int)(0xFFFFFFFFu - (unsigned)(key & 0xFFFFFFFFu));
            float val = __uint_as_float(bits);
            float plog = log2f(val);
            float fy = (float)(idx >> 8);
            float z = fmaxf(depth[b * NPIX + idx], 0.001f);
            float r = fminf(fmaxf(14.f / z, 1.5f), 18.f);
            float s2 = 0.36f * r * r;                      // (0.6*r)^2
            float c = 1.44269504f / (2.f * s2 + 1e-6f);    // log2(e)/denom
            float dymin = 0.f;
            if (fy < (float)y0) dymin = (float)y0 - fy;
            else if (fy > (float)(y0 + 3)) dymin = fy - (float)(y0 + 3);
            if (plog - dymin * dymin * c >= thr) {
                unsigned p = atomicAdd(&fcnt, 1u);
                lpf[p] = make_float4(plog, (float)(idx & 255), fy, c);
            }
        }
    }
    __syncthreads();                                       // barrier 6
    int m = (int)fcnt;

    // ---- log-domain splat, 4 rows/block, fused 1/vmax normalization ----
    float fx = (float)tid, fyv = (float)y0;
    float g0 = -INFINITY, g1 = -INFINITY, g2 = -INFINITY, g3 = -INFINITY;
    #pragma unroll 4
    for (int k = 0; k < m; ++k) {
        float4 q = lpf[k];                   // {plog, px, py, c}
        float dx = fx - q.y;
        float dx2 = dx * dx;
        float dy = fyv - q.z;
        float d2;
        d2 = fmaf(dy, dy, dx2);              g0 = fmaxf(g0, fmaf(-d2, q.w, q.x));
        float dyb = dy + 1.f;
        d2 = fmaf(dyb, dyb, dx2);            g1 = fmaxf(g1, fmaf(-d2, q.w, q.x));
        float dyc = dy + 2.f;
        d2 = fmaf(dyc, dyc, dx2);            g2 = fmaxf(g2, fmaf(-d2, q.w, q.x));
        float dyd = dy + 3.f;
        d2 = fmaf(dyd, dyd, dx2);            g3 = fmaxf(g3, fmaf(-d2, q.w, q.x));
    }
    float inv = 1.f / (vmax + 1e-6f);
    int base = (b * HH + y0) * WW + tid;
    out[base]          = exp2f(g0) * inv;
    out[base + WW]     = exp2f(g1) * inv;
    out[base + 2 * WW] = exp2f(g2) * inv;
    out[base + 3 * WW] = exp2f(g3) * inv;
}

extern "C" void kernel_launch(void* const* d_in, const int* in_sizes, int n_in,
                              void* d_out, int out_size, void* d_ws, size_t ws_size,
                              hipStream_t stream) {
    const float* vsm   = (const float*)d_in[0];
    const float* depth = (const float*)d_in[1];
    float* out = (float*)d_out;

    // workspace layout
    float* prod  = (float*)d_ws;                       // TOT
    unsigned* pmnG  = (unsigned*)(prod + TOT);         // BB (atomicMin, init 0xFF)
    unsigned* bcnt  = pmnG + BB;                       // BB
    unsigned* histg = bcnt + BB;                       // BB*SELBINS (16B-aligned offset)
    ull* candK = (ull*)(histg + BB * SELBINS);         // BB*CAP (8B-aligned)

    // init pmnG to +max-uint each call (first atomicMin always wins; deterministic across replays)
    hipMemsetAsync(pmnG, 0xFF, BB * sizeof(unsigned), stream);

    k_box9  <<<NBLK, 256, 0, stream>>>(vsm, prod, pmnG, histg, bcnt);
    k_nms   <<<NBLK, 256, 0, stream>>>(vsm, prod, pmnG, bcnt, candK, histg);
    k_tsplat<<<NBLK, 256, 0, stream>>>(depth, bcnt, candK, histg, out);
}

// Round 19
// 34.474 us; speedup vs baseline: 1.4675x; 1.3260x over previous
//
#include <hip/hip_runtime.h>
#include <float.h>
#include <math.h>

#define BB 8
#define HH 256
#define WW 256
#define NPIX 65536          // HH*WW
#define TOT (BB*NPIX)
#define KTOP 80
#define NTIL 64             // 8x8 tiles of 32x32 per image
#define TCAP 128            // max peaks per 32x32 tile (5x5 NMS spacing caps ~121)
#define CAP 8192            // max candidates per batch
#define SELBINS 4096        // bits>>19
#define BNDCAP 1024
#define NBLK (BB*NTIL)      // 512
#define PREF 12             // prefetch rounds in tsplat (covers nC <= 3072)
typedef unsigned long long ull;

// ============ fused 9x9 avg-pools -> prod, per-block min partials; zero hist+bcnt ============
__global__ void k_box9(const float* __restrict__ vsm, float* __restrict__ prod,
                       float* __restrict__ pmn,
                       unsigned* __restrict__ histg, unsigned* __restrict__ bcnt) {
    int blk = blockIdx.x;
    int b = blk >> 6, t = blk & 63;
    int ty0 = (t >> 3) << 5, tx0 = (t & 7) << 5;
    int tid = threadIdx.x;

    if (tid < 64) histg[b * SELBINS + t * 64 + tid] = 0u;
    if (blk < BB && tid == 0) bcnt[blk] = 0u;

    __shared__ float val[40][40];
    __shared__ float rs_o[40][32];
    __shared__ float rs_m[40][32];
    for (int i = tid; i < 1600; i += 256) {
        int ly = i / 40, lx = i - ly * 40;
        int gy = ty0 - 4 + ly, gx = tx0 - 4 + lx;
        float v = 0.f;
        if (gy >= 0 && gy < HH && gx >= 0 && gx < WW) v = vsm[(b * HH + gy) * WW + gx];
        val[ly][lx] = v;
    }
    __syncthreads();
    for (int i = tid; i < 1280; i += 256) {
        int ly = i >> 5, lx = i & 31;
        float so = 0.f, sm = 0.f;
        #pragma unroll
        for (int d = 0; d < 9; ++d) { float v = val[ly][lx + d]; so += (v > 0.2f) ? 1.f : 0.f; sm += v; }
        rs_o[ly][lx] = so; rs_m[ly][lx] = sm;
    }
    __syncthreads();
    int ox = tid & 31, oy0 = (tid >> 5) << 2;
    float tmn = FLT_MAX;
    #pragma unroll
    for (int j = 0; j < 4; ++j) {
        int oy = oy0 + j;
        float so = 0.f, sm = 0.f;
        #pragma unroll
        for (int d = 0; d < 9; ++d) { so += rs_o[oy + d][ox]; sm += rs_m[oy + d][ox]; }
        float p = (so * (1.f / 81.f)) * (sm * (1.f / 81.f));
        prod[(b * HH + ty0 + oy) * WW + tx0 + ox] = p;
        tmn = fminf(tmn, p);
    }
    #pragma unroll
    for (int o = 32; o > 0; o >>= 1) tmn = fminf(tmn, __shfl_xor(tmn, o, 64));
    __shared__ float wmn[4];
    if ((tid & 63) == 0) wmn[tid >> 6] = tmn;
    __syncthreads();
    if (tid == 0) pmn[blk] = fminf(fminf(wmn[0], wmn[1]), fminf(wmn[2], wmn[3]));
}

// ============ score = vsm*(prod-mn) + 5x5 NMS + per-batch compact (packed keys) + histogram ============
__global__ void k_nms(const float* __restrict__ vsm, const float* __restrict__ prod,
                      const float* __restrict__ pmn,
                      unsigned* __restrict__ bcnt, ull* __restrict__ candK,
                      unsigned* __restrict__ histg) {
    int blk = blockIdx.x;
    int b = blk >> 6, t = blk & 63;
    int ty0 = (t >> 3) << 5, tx0 = (t & 7) << 5;
    int tid = threadIdx.x;

    // ---- hoist halo loads (independent of mnp) so they overlap the pmn reduce ----
    float hv[6], hp[6];
    #pragma unroll
    for (int u = 0; u < 6; ++u) {
        int i = tid + u * 256;
        int ly = i / 36, lx = i - ly * 36;
        int gy = ty0 - 2 + ly, gx = tx0 - 2 + lx;
        bool ok = (i < 1296) && gy >= 0 && gy < HH && gx >= 0 && gx < WW;
        int idx = ok ? (b * HH + gy) * WW + gx : 0;
        hv[u] = vsm[idx];
        hp[u] = prod[idx];
    }

    __shared__ float sredn;
    if (tid < 64) {
        float mn = pmn[b * NTIL + tid];
        #pragma unroll
        for (int o = 32; o > 0; o >>= 1) mn = fminf(mn, __shfl_xor(mn, o, 64));
        if (tid == 0) sredn = mn;
    }
    __syncthreads();
    float mnp = sredn;

    __shared__ float sc[36][36];
    __shared__ float hm[36][32];
    #pragma unroll
    for (int u = 0; u < 6; ++u) {
        int i = tid + u * 256;
        if (i < 1296) {
            int ly = i / 36, lx = i - ly * 36;
            int gy = ty0 - 2 + ly, gx = tx0 - 2 + lx;
            bool ok = gy >= 0 && gy < HH && gx >= 0 && gx < WW;
            sc[ly][lx] = ok ? hv[u] * (hp[u] - mnp) : -FLT_MAX;
        }
    }
    __syncthreads();
    for (int i = tid; i < 1152; i += 256) {
        int ly = i >> 5, lx = i & 31;
        float m = sc[ly][lx];
        #pragma unroll
        for (int d = 1; d < 5; ++d) m = fmaxf(m, sc[ly][lx + d]);
        hm[ly][lx] = m;
    }
    __syncthreads();
    __shared__ unsigned scnt;
    __shared__ unsigned sbase;
    __shared__ float bv[TCAP];
    __shared__ int bi[TCAP];
    if (tid == 0) scnt = 0;
    __syncthreads();
    int ox = tid & 31, oy0 = (tid >> 5) << 2;
    #pragma unroll
    for (int j = 0; j < 4; ++j) {
        int oy = oy0 + j;
        float m = hm[oy][ox];
        #pragma unroll
        for (int d = 1; d < 5; ++d) m = fmaxf(m, hm[oy + d][ox]);
        float s = sc[oy + 2][ox + 2];
        if (s == m && s > 0.f) {
            unsigned p = atomicAdd(&scnt, 1u);
            if (p < TCAP) { bv[p] = s; bi[p] = (ty0 + oy) * WW + tx0 + ox; }
        }
    }
    __syncthreads();
    unsigned cnt = min(scnt, (unsigned)TCAP);
    if (tid == 0) sbase = cnt ? atomicAdd(&bcnt[b], cnt) : 0u;   // ONE global atomic per tile
    __syncthreads();
    unsigned base = sbase;
    for (unsigned i = tid; i < cnt; i += 256) {
        unsigned pos = base + i;
        if (pos < CAP) {
            unsigned bits = __float_as_uint(bv[i]);
            candK[b * CAP + pos] = ((ull)bits << 32) | (ull)(0xFFFFFFFFu - (unsigned)bi[i]);
            atomicAdd(&histg[b * SELBINS + (bits >> 19)], 1u);
        }
    }
}

// ============ fused: thin per-block top-80 set + log-domain splat + normalization ============
__global__ void __launch_bounds__(256)
k_tsplat(const float* __restrict__ depth, const unsigned* __restrict__ bcnt,
         const ull* __restrict__ candK, const unsigned* __restrict__ histg,
         float* __restrict__ out) {
    int blk = blockIdx.x;
    int b = blk >> 6;
    int y0 = (blk & 63) << 2;
    int tid = threadIdx.x;
    int lane = tid & 63;
    int wid = tid >> 6;

    __shared__ ull acc[KTOP];
    __shared__ ull bnd[BNDCAP];
    __shared__ float4 lpf[KTOP];
    __shared__ unsigned wtot[4];
    __shared__ int sB;
    __shared__ unsigned nAccS, nBndS, svm, fcnt;

    if (tid == 0) { sB = 0; nAccS = 0; nBndS = 0; svm = 0; fcnt = 0; }
    if (tid < KTOP) acc[tid] = 0ull;

    // ---- prefetch candidate keys (independent of B) so they overlap the hist scan ----
    int nC = min((int)bcnt[b], CAP);
    ull kreg[PREF];
    #pragma unroll
    for (int u = 0; u < PREF; ++u) {
        int i = tid + u * 256;
        kreg[u] = (i < nC) ? candK[b * CAP + i] : 0ull;   // real keys are nonzero (val>0)
    }
    __syncthreads();                                       // barrier 1

    // ---- hierarchical suffix scan of prebuilt histogram (shfl-based) ----
    {
        const unsigned* hg = histg + b * SELBINS;
        int j0 = tid * 16;
        unsigned h[16]; unsigned part = 0;
        #pragma unroll
        for (int j = 0; j < 16; j += 4) {
            uint4 q = *reinterpret_cast<const uint4*>(hg + j0 + j);
            h[j] = q.x; h[j+1] = q.y; h[j+2] = q.z; h[j+3] = q.w;
            part += q.x + q.y + q.z + q.w;
        }
        unsigned suf = part;                               // inclusive suffix within wave
        #pragma unroll
        for (int off = 1; off < 64; off <<= 1) {
            unsigned v = __shfl_down(suf, off, 64);
            if (lane + off < 64) suf += v;
        }
        if (lane == 0) wtot[wid] = suf;                    // wave total
        __syncthreads();                                   // barrier 2
        unsigned above_waves = 0;
        #pragma unroll
        for (int w = 0; w < 4; ++w) if (w > wid) above_waves += wtot[w];
        unsigned run = above_waves + (suf - part);         // suffix over threads > tid
        for (int j = 15; j >= 0; --j) {
            unsigned hj = h[j];
            run += hj;                                     // run == suffix(j0+j)
            if (run >= KTOP && run - hj < KTOP) sB = j0 + j;
        }
        __syncthreads();                                   // barrier 3
    }
    int B = sB;

    // ---- filter prefetched keys: bins>B unsorted accept, bin==B staged ----
    #pragma unroll
    for (int u = 0; u < PREF; ++u) {
        ull key = kreg[u];
        if (key) {
            unsigned bits = (unsigned)(key >> 32);
            int bin = (int)(bits >> 19);
            if (bin >= B) {
                atomicMax(&svm, bits);                     // vmax (positive: bit order == value order)
                if (bin > B) {
                    unsigned p = atomicAdd(&nAccS, 1u);
                    if (p < KTOP) acc[p] = key;            // suffix(B+1) < 80 by scan construction
                } else {
                    unsigned q2 = atomicAdd(&nBndS, 1u);
                    if (q2 < BNDCAP) bnd[q2] = key;
                }
            }
        }
    }
    // tail (only if nC > PREF*256)
    for (int i = tid + PREF * 256; i < nC; i += 256) {
        ull key = candK[b * CAP + i];
        unsigned bits = (unsigned)(key >> 32);
        int bin = (int)(bits >> 19);
        if (bin >= B) {
            atomicMax(&svm, bits);
            if (bin > B) {
                unsigned p = atomicAdd(&nAccS, 1u);
                if (p < KTOP) acc[p] = key;
            } else {
                unsigned q2 = atomicAdd(&nBndS, 1u);
                if (q2 < BNDCAP) bnd[q2] = key;
            }
        }
    }
    __syncthreads();                                       // barrier 4
    unsigned nAcc = min(nAccS, (unsigned)KTOP);
    unsigned nBnd = min(nBndS, (unsigned)BNDCAP);
    unsigned quota = (KTOP > nAcc) ? (KTOP - nAcc) : 0u;
    if (quota > nBnd) quota = nBnd;

    // ---- parallel rank-select in boundary bin (LDS broadcast; keys distinct -> exact set) ----
    for (int i = tid; i < (int)nBnd; i += 256) {
        ull mykey = bnd[i];
        unsigned rank = 0;
        for (unsigned j = 0; j < nBnd; ++j) rank += (bnd[j] > mykey) ? 1u : 0u;
        if (rank < quota) acc[nAcc + rank] = mykey;
    }
    __syncthreads();                                       // barrier 5

    // ---- peak params + y-band prune into lpf ----
    float vmax = __uint_as_float(svm);
    float thr = log2f(vmax + 1e-30f) - 11.f;               // drop contributions < 2^-11 * vmax
    unsigned nTot = nAcc + quota;
    if (tid < (int)nTot) {
        ull key = acc[tid];
        if (key) {
            unsigned bits = (unsigned)(key >> 32);
            int idx = (int)(0xFFFFFFFFu - (unsigned)(key & 0xFFFFFFFFu));
            float val = __uint_as_float(bits);
            float plog = log2f(val);
            float fy = (float)(idx >> 8);
            float z = fmaxf(depth[b * NPIX + idx], 0.001f);
            float r = fminf(fmaxf(14.f / z, 1.5f), 18.f);
            float s2 = 0.36f * r * r;                      // (0.6*r)^2
            float c = 1.44269504f / (2.f * s2 + 1e-6f);    // log2(e)/denom
            float dymin = 0.f;
            if (fy < (float)y0) dymin = (float)y0 - fy;
            else if (fy > (float)(y0 + 3)) dymin = fy - (float)(y0 + 3);
            if (plog - dymin * dymin * c >= thr) {
                unsigned p = atomicAdd(&fcnt, 1u);
                lpf[p] = make_float4(plog, (float)(idx & 255), fy, c);
            }
        }
    }
    __syncthreads();                                       // barrier 6
    int m = (int)fcnt;

    // ---- log-domain splat, 4 rows/block, fused 1/vmax normalization ----
    float fx = (float)tid, fyv = (float)y0;
    float g0 = -INFINITY, g1 = -INFINITY, g2 = -INFINITY, g3 = -INFINITY;
    #pragma unroll 4
    for (int k = 0; k < m; ++k) {
        float4 q = lpf[k];                   // {plog, px, py, c}
        float dx = fx - q.y;
        float dx2 = dx * dx;
        float dy = fyv - q.z;
        float d2;
        d2 = fmaf(dy, dy, dx2);              g0 = fmaxf(g0, fmaf(-d2, q.w, q.x));
        float dyb = dy + 1.f;
        d2 = fmaf(dyb, dyb, dx2);            g1 = fmaxf(g1, fmaf(-d2, q.w, q.x));
        float dyc = dy + 2.f;
        d2 = fmaf(dyc, dyc, dx2);            g2 = fmaxf(g2, fmaf(-d2, q.w, q.x));
        float dyd = dy + 3.f;
        d2 = fmaf(dyd, dyd, dx2);            g3 = fmaxf(g3, fmaf(-d2, q.w, q.x));
    }
    float inv = 1.f / (vmax + 1e-6f);
    int base = (b * HH + y0) * WW + tid;
    out[base]          = exp2f(g0) * inv;
    out[base + WW]     = exp2f(g1) * inv;
    out[base + 2 * WW] = exp2f(g2) * inv;
    out[base + 3 * WW] = exp2f(g3) * inv;
}

extern "C" void kernel_launch(void* const* d_in, const int* in_sizes, int n_in,
                              void* d_out, int out_size, void* d_ws, size_t ws_size,
                              hipStream_t stream) {
    const float* vsm   = (const float*)d_in[0];
    const float* depth = (const float*)d_in[1];
    float* out = (float*)d_out;

    // workspace layout
    float* prod  = (float*)d_ws;                       // TOT
    float* pmn   = prod + TOT;                         // NBLK
    unsigned* bcnt  = (unsigned*)(pmn + NBLK);         // BB
    unsigned* histg = bcnt + BB;                       // BB*SELBINS (16B-aligned offset)
    ull* candK = (ull*)(histg + BB * SELBINS);         // BB*CAP (8B-aligned)

    k_box9  <<<NBLK, 256, 0, stream>>>(vsm, prod, pmn, histg, bcnt);
    k_nms   <<<NBLK, 256, 0, stream>>>(vsm, prod, pmn, bcnt, candK, histg);
    k_tsplat<<<NBLK, 256, 0, stream>>>(depth, bcnt, candK, histg, out);
}